// Round 15
// baseline (523.707 us; speedup 1.0000x reference)
//
#include <hip/hip_runtime.h>
#include <hip/hip_bf16.h>
#include <stdint.h>

typedef unsigned short u16;
typedef __attribute__((ext_vector_type(8))) short short8;
typedef __attribute__((ext_vector_type(8))) unsigned short u16x8;
typedef __attribute__((ext_vector_type(4))) float f32x4;
typedef __attribute__((ext_vector_type(16))) float f32x16;

#define B_    2
#define S_    2048
#define H_    32
#define HKV_  8
#define D_    128
#define HID_  4096
#define QKVW_ 6144

__device__ __forceinline__ u16 f2bf(float f){
  uint32_t b = __builtin_bit_cast(uint32_t, f);
  b += 0x7FFFu + ((b >> 16) & 1u);
  return (u16)(b >> 16);
}
__device__ __forceinline__ float bf2f(u16 h){
  uint32_t b = ((uint32_t)h) << 16;
  return __builtin_bit_cast(float, b);
}
__device__ __forceinline__ u16 bfc(float f){
  __hip_bfloat16 h = __float2bfloat16(f);
  return __builtin_bit_cast(u16, h);
}
__device__ __forceinline__ uint32_t cvtpk(float a, float b){
  uint32_t r;
  asm("v_cvt_pk_bf16_f32 %0, %1, %2" : "=v"(r) : "v"(a), "v"(b));
  return r;
}
// v_permlane32_swap_b32 vdst, vsrc : vdst.hi(lanes32-63) <-> vsrc.lo(lanes0-31)
__device__ __forceinline__ void pl32swap(uint32_t &a, uint32_t &b){
  asm volatile("v_permlane32_swap_b32 %0, %1" : "+v"(a), "+v"(b));
}

__device__ __forceinline__ void gload16(const u16* g, u16* l){
  __builtin_amdgcn_global_load_lds((const __attribute__((address_space(1))) void*)g,
                                   (__attribute__((address_space(3))) void*)l, 16, 0, 0);
}

// ---------------- fused fp32 -> bf16 convert for all three inputs ----------------
__global__ void cvt3_kernel(const float* __restrict__ a, const float* __restrict__ b,
                            const float* __restrict__ c, u16* __restrict__ da,
                            u16* __restrict__ db, u16* __restrict__ dc){
  const int n1 = HID_*HID_/4;
  const int n2 = n1 + QKVW_*HID_/4;
  const int n3 = n2 + HID_*HID_/4;
  int i = blockIdx.x * blockDim.x + threadIdx.x;
  int stride = gridDim.x * blockDim.x;
  for (; i < n3; i += stride){
    const float* s; u16* d; int j;
    if (i < n1){ s = a; d = da; j = i; }
    else if (i < n2){ s = b; d = db; j = i - n1; }
    else { s = c; d = dc; j = i - n2; }
    float4 v = reinterpret_cast<const float4*>(s)[j];
    union { u16 u[4]; unsigned long long ll; } o;
    o.u[0] = f2bf(v.x); o.u[1] = f2bf(v.y); o.u[2] = f2bf(v.z); o.u[3] = f2bf(v.w);
    reinterpret_cast<unsigned long long*>(d)[j] = o.ll;
  }
}

// ---------------- RoPE table: tab[pos*64+p] = (cos, sin) ----------------
__global__ void rope_table_kernel(float2* __restrict__ tab){
  int idx = blockIdx.x * blockDim.x + threadIdx.x;
  if (idx >= S_ * 64) return;
  int pos = idx >> 6, p = idx & 63;
  float inv = powf(10000.0f, -(float)p / 64.0f);
  float ang = (float)pos * inv;
  tab[idx] = make_float2(cosf(ang), sinf(ang));
}

// ---------------- RoPE apply to K only (in-place, no scale) ----------------
__global__ void rope_k_kernel(u16* __restrict__ qkv, const int* __restrict__ pos_ids,
                              const float2* __restrict__ tab){
  int t = blockIdx.x;
  int pos = pos_ids[t];
  const float2* tb = tab + pos * 64;
  u16* row = qkv + (size_t)t * QKVW_ + HID_;
  for (int it = threadIdx.x; it < HKV_ * 64; it += 256){
    int hh = it >> 6, p = it & 63;
    int base = hh * D_;
    float x1 = bf2f(row[base + p]);
    float x2 = bf2f(row[base + 64 + p]);
    float2 cs = tb[p];
    row[base + p]      = f2bf(x1 * cs.x - x2 * cs.y);
    row[base + 64 + p] = f2bf(x2 * cs.x + x1 * cs.y);
  }
}

#define MFMA_(a, b, c)   __builtin_amdgcn_mfma_f32_16x16x32_bf16((a), (b), (c), 0, 0, 0)
#define MFMA32_(a, b, c) __builtin_amdgcn_mfma_f32_32x32x16_bf16((a), (b), (c), 0, 0, 0)

// ---------------- 128x128 GEMM (proven 880 TF structure): C = A * B^T, bf16 out ----------------
// NOTE: 880 TF is conditional on VGPR=76 -> 3 blocks/CU. Do NOT add epilogue state
// (R13: +2 pointers/branch -> 108 VGPR -> 2 blocks/CU -> 314 us).
__global__ __launch_bounds__(256) void gemm128(const u16* __restrict__ A, const u16* __restrict__ B,
                                               u16* __restrict__ C, int M, int N, int K){
  __shared__ u16 As[128*64];
  __shared__ u16 Bs[128*64];
  const int tid  = threadIdx.x;
  const int wave = tid >> 6, lane = tid & 63;
  const int hi = lane >> 4, lo = lane & 15;
  const int bn = blockIdx.x, bm = blockIdx.y;
  const int wm = (wave >> 1) * 64, wn = (wave & 1) * 64;
  f32x4 acc[4][4] = {};

  const u16* ap[4]; const u16* bp[4];
  u16* lA[4]; u16* lB[4];
  #pragma unroll
  for (int p = 0; p < 4; p++){
    int e   = p*2048 + wave*512 + lane*8;
    int row = e >> 6;
    int cs  = ((e >> 3) & 7) ^ (row & 7);
    ap[p] = A + (size_t)(bm*128 + row) * K + cs*8;
    bp[p] = B + (size_t)(bn*128 + row) * K + cs*8;
    lA[p] = &As[p*2048 + wave*512];
    lB[p] = &Bs[p*2048 + wave*512];
  }
  const int sw = lo & 7;
  const int nk = K >> 6;
  for (int t = 0; t < nk; t++){
    #pragma unroll
    for (int p = 0; p < 4; p++){
      gload16(ap[p], lA[p]);
      gload16(bp[p], lB[p]);
      ap[p] += 64; bp[p] += 64;
    }
    __syncthreads();
    #pragma unroll
    for (int kk = 0; kk < 2; kk++){
      short8 af[4], bf[4];
      int sz = ((kk*4 + hi) ^ sw) * 8;
      #pragma unroll
      for (int mt = 0; mt < 4; mt++) af[mt] = *(const short8*)&As[(wm + mt*16 + lo)*64 + sz];
      #pragma unroll
      for (int nt = 0; nt < 4; nt++) bf[nt] = *(const short8*)&Bs[(wn + nt*16 + lo)*64 + sz];
      #pragma unroll
      for (int mt = 0; mt < 4; mt++)
        #pragma unroll
        for (int nt = 0; nt < 4; nt++)
          acc[mt][nt] = MFMA_(af[mt], bf[nt], acc[mt][nt]);
    }
    __syncthreads();
  }
  #pragma unroll
  for (int mt = 0; mt < 4; mt++){
    int row = bm*128 + wm + mt*16 + 4*hi;
    #pragma unroll
    for (int nt = 0; nt < 4; nt++){
      int col = bn*128 + wn + nt*16 + lo;
      #pragma unroll
      for (int r = 0; r < 4; r++)
        C[(size_t)(row + r)*N + col] = f2bf(acc[mt][nt][r]);
    }
  }
}

// ---------------- 256x256 GEMM, m201-style 8-phase (4 phases/K-tile, half-tile staging) -------
// Wave mapping interleaved across LDS halves: M row = q*128 + wr*64 + mt*16 (q = A-half),
// N col = n*128 + wc*32 + nt*16 (n = B-half). Per tile: p1 reads A0(8)+B0(4), computes q0n0;
// p2 reads A1(8), q1n0 (B0 held); p3 reads B1(4), q1n1 (A1 held); p4 re-reads A0(8), q0n1
// (B1 held). Stages: p1->A0(t+1) [other dbuf], p2->B0(t+2), p3->A1(t+2), p4->B1(t+2)
// [same dbuf, each after its region's last read]. vmcnt(6) once per tile at p4 (per-wave
// FIFO: waits the 4-phase-old stage). Consume/stage gaps all >= 4 phases.
template<int CF>
__global__ __launch_bounds__(512, 2) void gemm256p8(const u16* __restrict__ A, const u16* __restrict__ B,
                                                    void* __restrict__ Cv, int M, int N, int K, int nbn){
  __shared__ u16 As[2][2][8192];   // [dbuf][half][128*64]
  __shared__ u16 Bs[2][2][8192];
  const int tid = threadIdx.x;
  const int wave = tid >> 6, lane = tid & 63, lo = lane & 15, hi = lane >> 4;
  const int wr = (wave >> 2) & 1, wc = wave & 3;
  const int sw = lo & 7;

  const int nwg = gridDim.x, bid = blockIdx.x, cpx = nwg >> 3;
  const int wg = (bid & 7) * cpx + (bid >> 3);
  const int bm = wg / nbn, bn = wg - bm * nbn;

  f32x4 acc[2][4][2][2] = {};      // [q][mt][n][nt]

  const int pr0 = tid >> 3;
  const int sc0 = (tid & 7) ^ (pr0 & 7);
  const u16* aSrc[2][2]; const u16* bSrc[2][2];
  #pragma unroll
  for (int h = 0; h < 2; h++)
    #pragma unroll
    for (int j = 0; j < 2; j++){
      aSrc[h][j] = A + (size_t)(bm*256 + h*128 + j*64 + pr0)*K + sc0*8;
      bSrc[h][j] = B + (size_t)(bn*256 + h*128 + j*64 + pr0)*K + sc0*8;
    }
  const int dOfs = tid * 8;

  #define STG_A(d, h, ko) { gload16(aSrc[h][0] + (ko), &As[d][h][dOfs]); \
                            gload16(aSrc[h][1] + (ko), &As[d][h][4096 + dOfs]); }
  #define STG_B(d, h, ko) { gload16(bSrc[h][0] + (ko), &Bs[d][h][dOfs]); \
                            gload16(bSrc[h][1] + (ko), &Bs[d][h][4096 + dOfs]); }
  // A-frags for quadrant q from As[d][q]; B-frags for half n from Bs[d][n]
  #define RD_AF(d, q) \
    _Pragma("unroll") for (int mt = 0; mt < 4; mt++) \
      _Pragma("unroll") for (int kk = 0; kk < 2; kk++) \
        af[mt*2+kk] = *(const short8*)&As[d][q][(wr*64 + mt*16 + lo)*64 + ((((kk<<2)+hi)^sw)<<3)];
  #define RD_BF(dst, d, n) \
    _Pragma("unroll") for (int nt = 0; nt < 2; nt++) \
      _Pragma("unroll") for (int kk = 0; kk < 2; kk++) \
        dst[nt*2+kk] = *(const short8*)&Bs[d][n][(wc*32 + nt*16 + lo)*64 + ((((kk<<2)+hi)^sw)<<3)];
  #define DO_MFMA(q, n, bfv) \
    __builtin_amdgcn_s_setprio(1); \
    _Pragma("unroll") for (int mt = 0; mt < 4; mt++) \
      _Pragma("unroll") for (int nt = 0; nt < 2; nt++) \
        _Pragma("unroll") for (int kk = 0; kk < 2; kk++) \
          acc[q][mt][n][nt] = MFMA_(af[mt*2+kk], bfv[nt*2+kk], acc[q][mt][n][nt]); \
    __builtin_amdgcn_s_setprio(0);

  const int nk = K >> 6;
  // prologue: tile 0 full (A0,B0,A1,B1) + tile 1 (B0,A1,B1); A0(1) staged at t=0.p1
  STG_A(0, 0, 0) STG_B(0, 0, 0) STG_A(0, 1, 0) STG_B(0, 1, 0)
  if (nk > 1){ STG_B(1, 0, 64) STG_A(1, 1, 64) STG_B(1, 1, 64)
    asm volatile("s_waitcnt vmcnt(6)" ::: "memory");
  } else {
    asm volatile("s_waitcnt vmcnt(0)" ::: "memory");
  }
  __builtin_amdgcn_s_barrier();

  for (int t = 0; t < nk; ++t){
    const int d = t & 1, dn = d ^ 1;
    const size_t ko1 = (size_t)(t+1) * 64, ko2 = (size_t)(t+2) * 64;
    const bool m1 = (t + 1 < nk), m2 = (t + 2 < nk);
    short8 af[8], bf0[4], bf1[4];

    // ---- p1: read A0 + B0; compute q0n0; stage A0(t+1) -> other dbuf ----
    RD_AF(d, 0)
    RD_BF(bf0, d, 0)
    if (m1){ STG_A(dn, 0, ko1) }
    __builtin_amdgcn_s_barrier();
    DO_MFMA(0, 0, bf0)
    __builtin_amdgcn_s_barrier();

    // ---- p2: read A1; compute q1n0 (B0 held); stage B0(t+2) [B0(t) last read p1] ----
    RD_AF(d, 1)
    if (m2){ STG_B(d, 0, ko2) }
    __builtin_amdgcn_s_barrier();
    DO_MFMA(1, 0, bf0)
    __builtin_amdgcn_s_barrier();

    // ---- p3: read B1; compute q1n1 (A1 held); stage A1(t+2) [A1(t) last read p2] ----
    RD_BF(bf1, d, 1)
    if (m2){ STG_A(d, 1, ko2) }
    __builtin_amdgcn_s_barrier();
    DO_MFMA(1, 1, bf1)
    __builtin_amdgcn_s_barrier();

    // ---- p4: re-read A0; compute q0n1 (B1 held); stage B1(t+2); counted vmcnt ----
    RD_AF(d, 0)
    if (m2){
      STG_B(d, 1, ko2)
      asm volatile("s_waitcnt vmcnt(6)" ::: "memory");
    } else {
      asm volatile("s_waitcnt vmcnt(0)" ::: "memory");
    }
    __builtin_amdgcn_sched_barrier(0);
    __builtin_amdgcn_s_barrier();
    DO_MFMA(0, 1, bf1)
    __builtin_amdgcn_s_barrier();
  }
  #undef STG_A
  #undef STG_B
  #undef RD_AF
  #undef RD_BF
  #undef DO_MFMA

  #pragma unroll
  for (int q = 0; q < 2; q++)
    #pragma unroll
    for (int mt = 0; mt < 4; mt++){
      int row = bm*256 + q*128 + wr*64 + mt*16 + 4*hi;
      #pragma unroll
      for (int n = 0; n < 2; n++)
        #pragma unroll
        for (int nt = 0; nt < 2; nt++){
          int col = bn*256 + n*128 + wc*32 + nt*16 + lo;
          #pragma unroll
          for (int r = 0; r < 4; r++){
            if (CF == 0) ((u16*)Cv)[(size_t)(row + r)*N + col] = f2bf(acc[q][mt][n][nt][r]);
            else         ((float*)Cv)[(size_t)(row + r)*N + col] = acc[q][mt][n][nt][r];
          }
        }
    }
}

// ---------------- fused windowed-causal GQA flash attention (32x32 MFMA, QBLK=128) ----------------
// 1D grid 1024: id&7 = hkv (XCD pin), qt scrambled (+3*gb) for load balance.
// 4 waves x 32 q-rows. Swapped QK^T (A=K, B=Q). P -> PV A-frags via cvt_pk+permlane (T12).
// LDS 64 KB (K dbuf + V^T dbuf) -> 2 blocks/CU. VGPR needs ~200 -> 2 waves/SIMD is the
// floor (HW VGPR steps 64/128/256; min-3-waves bound forces spills -- measured R10).
__global__ __launch_bounds__(256, 2) void attn_kernel(const u16* __restrict__ qkv, u16* __restrict__ out,
                                                      const int* __restrict__ winp,
                                                      const int* __restrict__ pos_ids,
                                                      const float2* __restrict__ tab){
  const int id = blockIdx.x;
  const int hkv = id & 7;
  const int qtr = (id >> 3) & 15;
  const int gb  = id >> 7;
  const int qt  = (qtr + 3*gb) & 15;
  const int g = gb & 3, b = gb >> 2;
  const int h = hkv*4 + g;
  const int q0 = qt * 128;
  const int tid = threadIdx.x, wave = tid >> 6, lane = tid & 63;
  const int ql = lane & 31, hl = lane >> 5;
  const int win = winp[0];

  __shared__ u16 Ks[2][64*128];   // [j][d], 16-slot XOR swizzle (slot ^= j&15)
  __shared__ u16 VT[2][128*64];   // [d][j], 8-slot XOR swizzle (4-word groups)

  const int qw = q0 + wave*32;
  short8 qf[8];
  {
    const u16* qp = qkv + (size_t)(b*S_ + qw + ql)*QKVW_ + h*D_ + hl*8;
    #pragma unroll
    for (int c = 0; c < 8; c++) qf[c] = *(const short8*)(qp + c*16);
    const float QS = 0.08838834764831845f * 1.4426950408889634f;
    int pos = pos_ids[b*S_ + qw + ql];
    const float2* tb = tab + pos*64 + hl*8;
    #pragma unroll
    for (int c = 0; c < 4; c++)
      #pragma unroll
      for (int i = 0; i < 8; i++){
        float2 cs = tb[c*16 + i];
        float x1 = bf2f((u16)qf[c][i]), x2 = bf2f((u16)qf[c+4][i]);
        qf[c][i]   = (short)bfc((x1*cs.x - x2*cs.y) * QS);
        qf[c+4][i] = (short)bfc((x2*cs.x + x1*cs.y) * QS);
      }
  }

  f32x16 acc[4] = {};
  float m_r = -3.0e38f, l_r = 0.0f;

  int js = q0 - (win - 1); if (js < 0) js = 0; js &= ~63;
  const int nt = (q0 + 128 - js) >> 6;

  const u16* Kg = qkv + (size_t)HID_ + hkv*D_;
  const u16* Vg = qkv + (size_t)HID_ + HKV_*D_ + hkv*D_;
  const int jp = tid & 31, d0 = (tid >> 5) * 16;

  const u16* ksrc[4];
  #pragma unroll
  for (int p = 0; p < 4; p++){
    int e = p*256 + tid;
    int row = e >> 4;
    int ss = (e & 15) ^ (row & 15);
    ksrc[p] = Kg + (size_t)(b*S_ + js + row)*QKVW_ + ss*8;
  }
  const u16* vsrc = Vg + (size_t)(b*S_ + js + 2*jp)*QKVW_ + d0;

  u16x8 vr0, vr1, vr2, vr3;
  {
    #pragma unroll
    for (int p = 0; p < 4; p++) gload16(ksrc[p], &Ks[0][p*2048 + wave*512]);
    vr0 = *(const u16x8*)(vsrc);
    vr1 = *(const u16x8*)(vsrc + 8);
    vr2 = *(const u16x8*)(vsrc + QKVW_);
    vr3 = *(const u16x8*)(vsrc + QKVW_ + 8);
    uint32_t* VT32 = (uint32_t*)&VT[0][0];
    #pragma unroll
    for (int i = 0; i < 8; i++){
      int da = d0 + i, db = d0 + 8 + i;
      VT32[da*32 + (jp ^ ((da & 7) << 2))] = (uint32_t)vr0[i] | ((uint32_t)vr2[i] << 16);
      VT32[db*32 + (jp ^ ((db & 7) << 2))] = (uint32_t)vr1[i] | ((uint32_t)vr3[i] << 16);
    }
  }
  __syncthreads();

  for (int t = 0; t < nt; t++){
    const int jc = js + t*64;
    const int cur = t & 1, nxt = cur ^ 1;
    const bool more = (t + 1 < nt);
    if (more){
      const size_t adv = (size_t)(t+1) * 64 * QKVW_;
      #pragma unroll
      for (int p = 0; p < 4; p++) gload16(ksrc[p] + adv, &Ks[nxt][p*2048 + wave*512]);
      const u16* vp = vsrc + adv;
      vr0 = *(const u16x8*)(vp);
      vr1 = *(const u16x8*)(vp + 8);
      vr2 = *(const u16x8*)(vp + QKVW_);
      vr3 = *(const u16x8*)(vp + QKVW_ + 8);
    }
    if (jc <= qw + 31 && jc + 63 >= qw - win + 1){
      // ---- QK^T: A=K rows j, B=Q cols q ----
      f32x16 s0 = {}, s1 = {};
      const int sl = ql & 15;
      __builtin_amdgcn_s_setprio(1);
      #pragma unroll
      for (int c = 0; c < 8; c++){
        int so = (((c*2 + hl) ^ sl) * 8);
        short8 k0 = *(const short8*)&Ks[cur][ql*128 + so];
        short8 k1 = *(const short8*)&Ks[cur][(32 + ql)*128 + so];
        s0 = MFMA32_(k0, qf[c], s0);
        s1 = MFMA32_(k1, qf[c], s1);
      }
      __builtin_amdgcn_s_setprio(0);
      // ---- mask ----
      const int qa = qw + ql;
      const bool fullv = (jc + 63 <= qw) && (jc >= qw + 32 - win);
      if (!fullv){
        #pragma unroll
        for (int r = 0; r < 16; r++){
          int j0 = jc + (r&3) + 8*(r>>2) + 4*hl;
          if (j0 > qa || qa - j0 >= win) s0[r] = -3.0e38f;
          int j1 = j0 + 32;
          if (j1 > qa || qa - j1 >= win) s1[r] = -3.0e38f;
        }
      }
      // ---- row max (31 in-lane + 1 xor) ----
      float mx = s0[0];
      #pragma unroll
      for (int r = 1; r < 16; r++) mx = fmaxf(mx, s0[r]);
      #pragma unroll
      for (int r = 0; r < 16; r++) mx = fmaxf(mx, s1[r]);
      mx = fmaxf(mx, __shfl_xor(mx, 32));
      // ---- defer-max rescale (T13) ----
      if (__any(mx > m_r + 8.0f)){
        float mn = fmaxf(m_r, mx);
        float al = exp2f(m_r - mn);
        m_r = mn; l_r *= al;
        #pragma unroll
        for (int r = 0; r < 16; r++){
          float a = __shfl(al, (r&3) + 8*(r>>2) + 4*hl);
          acc[0][r] *= a; acc[1][r] *= a; acc[2][r] *= a; acc[3][r] *= a;
        }
      }
      // ---- exp2 (in place) + sum ----
      float ps = 0.f;
      if (fullv){
        #pragma unroll
        for (int r = 0; r < 16; r++){
          s0[r] = exp2f(s0[r] - m_r); s1[r] = exp2f(s1[r] - m_r);
          ps += s0[r] + s1[r];
        }
      } else {
        #pragma unroll
        for (int r = 0; r < 16; r++){
          s0[r] = s0[r] > -1e37f ? exp2f(s0[r] - m_r) : 0.f;
          s1[r] = s1[r] > -1e37f ? exp2f(s1[r] - m_r) : 0.f;
          ps += s0[r] + s1[r];
        }
      }
      ps += __shfl_xor(ps, 32);
      l_r += ps;
      // ---- P -> A-frags: cvt_pk + permlane32_swap (T12) ----
      short8 pa[4];
      #define MKFRAG(dst, P, o) { \
        uint32_t x1 = cvtpk(P[o+0], P[o+1]), x2 = cvtpk(P[o+2], P[o+3]); \
        uint32_t y1 = cvtpk(P[o+4], P[o+5]), y2 = cvtpk(P[o+6], P[o+7]); \
        pl32swap(x1, y1); pl32swap(x2, y2); \
        union { uint32_t w[4]; short8 v; } u_; \
        u_.w[0] = x1; u_.w[1] = x2; u_.w[2] = y1; u_.w[3] = y2; \
        dst = u_.v; }
      MKFRAG(pa[0], s0, 0)
      MKFRAG(pa[1], s0, 8)
      MKFRAG(pa[2], s1, 0)
      MKFRAG(pa[3], s1, 8)
      #undef MKFRAG
      // ---- PV: A=P (reg), B=V^T from LDS ----
      __builtin_amdgcn_s_setprio(1);
      #pragma unroll
      for (int dt = 0; dt < 4; dt++){
        const int dr = dt*32 + ql;
        const u16* vb = &VT[cur][dr*64];
        const int sb = dr & 7;
        #pragma unroll
        for (int ks = 0; ks < 4; ks++){
          short8 vf = *(const short8*)&vb[(((ks*2 + hl) ^ sb) * 8)];
          acc[dt] = MFMA32_(pa[ks], vf, acc[dt]);
        }
      }
      __builtin_amdgcn_s_setprio(0);
    }
    if (more){
      uint32_t* VT32 = (uint32_t*)&VT[nxt][0];
      #pragma unroll
      for (int i = 0; i < 8; i++){
        int da = d0 + i, db = d0 + 8 + i;
        VT32[da*32 + (jp ^ ((da & 7) << 2))] = (uint32_t)vr0[i] | ((uint32_t)vr2[i] << 16);
        VT32[db*32 + (jp ^ ((db & 7) << 2))] = (uint32_t)vr1[i] | ((uint32_t)vr3[i] << 16);
      }
      __syncthreads();
    }
  }
  // ---- epilogue ----
  #pragma unroll
  for (int r = 0; r < 16; r++){
    int qrow = (r&3) + 8*(r>>2) + 4*hl;
    float lr = __shfl(l_r, qrow);
    float invl = 1.0f / lr;
    size_t ro = (size_t)(b*S_ + qw + qrow)*HID_ + h*D_ + ql;
    out[ro     ] = f2bf(acc[0][r] * invl);
    out[ro + 32] = f2bf(acc[1][r] * invl);
    out[ro + 64] = f2bf(acc[2][r] * invl);
    out[ro + 96] = f2bf(acc[3][r] * invl);
  }
}

extern "C" void kernel_launch(void* const* d_in, const int* in_sizes, int n_in,
                              void* d_out, int out_size, void* d_ws, size_t ws_size,
                              hipStream_t stream) {
  const float* hs   = (const float*)d_in[0];
  const float* wqkv = (const float*)d_in[1];
  const float* wo   = (const float*)d_in[2];
  const int* pos  = (const int*)d_in[5];
  const int* winp = (const int*)d_in[7];
  float* out = (float*)d_out;

  u16* hsb = (u16*)d_ws;
  u16* wqb = hsb + (size_t)HID_*HID_;
  u16* wob = wqb + (size_t)QKVW_*HID_;
  u16* qkv = wob + (size_t)HID_*HID_;
  u16* att = qkv + (size_t)(B_*S_)*QKVW_;
  float2* tab = (float2*)(att + (size_t)(B_*S_)*HID_);

  cvt3_kernel<<<2048, 256, 0, stream>>>(hs, wqkv, wo, hsb, wqb, wob);
  rope_table_kernel<<<(S_*64 + 255)/256, 256, 0, stream>>>(tab);
  gemm128<<<dim3(QKVW_/128, (B_*S_)/128), 256, 0, stream>>>(hsb, wqb, qkv, B_*S_, QKVW_, HID_);
  rope_k_kernel<<<B_*S_, 256, 0, stream>>>(qkv, pos, tab);
  attn_kernel<<<1024, 256, 0, stream>>>(qkv, att, winp, pos, tab);
  gemm256p8<1><<<(B_*S_/256)*(HID_/256), 512, 0, stream>>>(att, wob, (void*)out, B_*S_, HID_, HID_, HID_/256);
}

// Round 16
// 520.670 us; speedup vs baseline: 1.0058x; 1.0058x over previous
//
#include <hip/hip_runtime.h>
#include <hip/hip_bf16.h>
#include <stdint.h>

typedef unsigned short u16;
typedef __attribute__((ext_vector_type(8))) short short8;
typedef __attribute__((ext_vector_type(8))) unsigned short u16x8;
typedef __attribute__((ext_vector_type(4))) float f32x4;
typedef __attribute__((ext_vector_type(16))) float f32x16;

#define B_    2
#define S_    2048
#define H_    32
#define HKV_  8
#define D_    128
#define HID_  4096
#define QKVW_ 6144

__device__ __forceinline__ u16 f2bf(float f){
  uint32_t b = __builtin_bit_cast(uint32_t, f);
  b += 0x7FFFu + ((b >> 16) & 1u);
  return (u16)(b >> 16);
}
__device__ __forceinline__ float bf2f(u16 h){
  uint32_t b = ((uint32_t)h) << 16;
  return __builtin_bit_cast(float, b);
}
__device__ __forceinline__ u16 bfc(float f){
  __hip_bfloat16 h = __float2bfloat16(f);
  return __builtin_bit_cast(u16, h);
}
__device__ __forceinline__ uint32_t cvtpk(float a, float b){
  uint32_t r;
  asm("v_cvt_pk_bf16_f32 %0, %1, %2" : "=v"(r) : "v"(a), "v"(b));
  return r;
}
// v_permlane32_swap_b32 vdst, vsrc : vdst.hi(lanes32-63) <-> vsrc.lo(lanes0-31)
__device__ __forceinline__ void pl32swap(uint32_t &a, uint32_t &b){
  asm volatile("v_permlane32_swap_b32 %0, %1" : "+v"(a), "+v"(b));
}

__device__ __forceinline__ void gload16(const u16* g, u16* l){
  __builtin_amdgcn_global_load_lds((const __attribute__((address_space(1))) void*)g,
                                   (__attribute__((address_space(3))) void*)l, 16, 0, 0);
}

// ---------------- fused fp32 -> bf16 convert (3 tensors) + RoPE table ----------------
__global__ void cvt3_kernel(const float* __restrict__ a, const float* __restrict__ b,
                            const float* __restrict__ c, u16* __restrict__ da,
                            u16* __restrict__ db, u16* __restrict__ dc,
                            float2* __restrict__ tab){
  const int n1 = HID_*HID_/4;
  const int n2 = n1 + QKVW_*HID_/4;
  const int n3 = n2 + HID_*HID_/4;
  const int n4 = n3 + S_*64;
  int i = blockIdx.x * blockDim.x + threadIdx.x;
  int stride = gridDim.x * blockDim.x;
  for (; i < n4; i += stride){
    if (i < n3){
      const float* s; u16* d; int j;
      if (i < n1){ s = a; d = da; j = i; }
      else if (i < n2){ s = b; d = db; j = i - n1; }
      else { s = c; d = dc; j = i - n2; }
      float4 v = reinterpret_cast<const float4*>(s)[j];
      union { u16 u[4]; unsigned long long ll; } o;
      o.u[0] = f2bf(v.x); o.u[1] = f2bf(v.y); o.u[2] = f2bf(v.z); o.u[3] = f2bf(v.w);
      reinterpret_cast<unsigned long long*>(d)[j] = o.ll;
    } else {
      int idx = i - n3;
      int pos = idx >> 6, p = idx & 63;
      float inv = powf(10000.0f, -(float)p / 64.0f);
      float ang = (float)pos * inv;
      tab[idx] = make_float2(cosf(ang), sinf(ang));
    }
  }
}

// ---------------- RoPE apply to K only (in-place, no scale) ----------------
__global__ void rope_k_kernel(u16* __restrict__ qkv, const int* __restrict__ pos_ids,
                              const float2* __restrict__ tab){
  int t = blockIdx.x;
  int pos = pos_ids[t];
  const float2* tb = tab + pos * 64;
  u16* row = qkv + (size_t)t * QKVW_ + HID_;
  for (int it = threadIdx.x; it < HKV_ * 64; it += 256){
    int hh = it >> 6, p = it & 63;
    int base = hh * D_;
    float x1 = bf2f(row[base + p]);
    float x2 = bf2f(row[base + 64 + p]);
    float2 cs = tb[p];
    row[base + p]      = f2bf(x1 * cs.x - x2 * cs.y);
    row[base + 64 + p] = f2bf(x2 * cs.x + x1 * cs.y);
  }
}

#define MFMA_(a, b, c)   __builtin_amdgcn_mfma_f32_16x16x32_bf16((a), (b), (c), 0, 0, 0)
#define MFMA32_(a, b, c) __builtin_amdgcn_mfma_f32_32x32x16_bf16((a), (b), (c), 0, 0, 0)

// ---------------- 128x128 GEMM (proven 880 TF structure): C = A * B^T, bf16 out ----------------
// NOTE: 880 TF is conditional on VGPR=76 -> 3 blocks/CU. Do NOT add epilogue state
// (R13: +2 pointers/branch -> 108 VGPR -> 2 blocks/CU -> 314 us).
__global__ __launch_bounds__(256) void gemm128(const u16* __restrict__ A, const u16* __restrict__ B,
                                               u16* __restrict__ C, int M, int N, int K){
  __shared__ u16 As[128*64];
  __shared__ u16 Bs[128*64];
  const int tid  = threadIdx.x;
  const int wave = tid >> 6, lane = tid & 63;
  const int hi = lane >> 4, lo = lane & 15;
  const int bn = blockIdx.x, bm = blockIdx.y;
  const int wm = (wave >> 1) * 64, wn = (wave & 1) * 64;
  f32x4 acc[4][4] = {};

  const u16* ap[4]; const u16* bp[4];
  u16* lA[4]; u16* lB[4];
  #pragma unroll
  for (int p = 0; p < 4; p++){
    int e   = p*2048 + wave*512 + lane*8;
    int row = e >> 6;
    int cs  = ((e >> 3) & 7) ^ (row & 7);
    ap[p] = A + (size_t)(bm*128 + row) * K + cs*8;
    bp[p] = B + (size_t)(bn*128 + row) * K + cs*8;
    lA[p] = &As[p*2048 + wave*512];
    lB[p] = &Bs[p*2048 + wave*512];
  }
  const int sw = lo & 7;
  const int nk = K >> 6;
  for (int t = 0; t < nk; t++){
    #pragma unroll
    for (int p = 0; p < 4; p++){
      gload16(ap[p], lA[p]);
      gload16(bp[p], lB[p]);
      ap[p] += 64; bp[p] += 64;
    }
    __syncthreads();
    #pragma unroll
    for (int kk = 0; kk < 2; kk++){
      short8 af[4], bf[4];
      int sz = ((kk*4 + hi) ^ sw) * 8;
      #pragma unroll
      for (int mt = 0; mt < 4; mt++) af[mt] = *(const short8*)&As[(wm + mt*16 + lo)*64 + sz];
      #pragma unroll
      for (int nt = 0; nt < 4; nt++) bf[nt] = *(const short8*)&Bs[(wn + nt*16 + lo)*64 + sz];
      #pragma unroll
      for (int mt = 0; mt < 4; mt++)
        #pragma unroll
        for (int nt = 0; nt < 4; nt++)
          acc[mt][nt] = MFMA_(af[mt], bf[nt], acc[mt][nt]);
    }
    __syncthreads();
  }
  #pragma unroll
  for (int mt = 0; mt < 4; mt++){
    int row = bm*128 + wm + mt*16 + 4*hi;
    #pragma unroll
    for (int nt = 0; nt < 4; nt++){
      int col = bn*128 + wn + nt*16 + lo;
      #pragma unroll
      for (int r = 0; r < 4; r++)
        C[(size_t)(row + r)*N + col] = f2bf(acc[mt][nt][r]);
    }
  }
}

// ---------------- 256x256 GEMM, 4-phase/K-tile counted-vmcnt schedule, fp32 out ----------------
// Used only where grid == 256 blocks (perfectly balanced at 1 block/CU). ~1150 TF measured;
// 8-phase half-tile-staged variant measured neutral (R15) -- this is the proven form.
__global__ __launch_bounds__(512, 2) void gemm256(const u16* __restrict__ A, const u16* __restrict__ B,
                                                  float* __restrict__ C, int M, int N, int K, int nbn){
  __shared__ u16 As[2][16384];
  __shared__ u16 Bs[2][16384];
  const int tid = threadIdx.x;
  const int wave = tid >> 6, lane = tid & 63, lo = lane & 15, hi = lane >> 4;
  const int wr = wave >> 2, wc = wave & 3;
  const int sw = lo & 7;

  const int nwg = gridDim.x, bid = blockIdx.x, cpx = nwg >> 3;
  const int wg = (bid & 7) * cpx + (bid >> 3);
  const int bm = wg / nbn, bn = wg - bm * nbn;

  f32x4 acc[8][4] = {};

  const int pr0 = tid >> 3;
  const int sc0 = (tid & 7) ^ (pr0 & 7);
  const u16* aS0 = A + ((size_t)(bm*256 + pr0      ))*K + sc0*8;
  const u16* aS1 = A + ((size_t)(bm*256 + pr0 + 128))*K + sc0*8;
  const u16* aS2 = A + ((size_t)(bm*256 + pr0 + 64 ))*K + sc0*8;
  const u16* aS3 = A + ((size_t)(bm*256 + pr0 + 192))*K + sc0*8;
  const u16* bS0 = B + ((size_t)(bn*256 + pr0      ))*K + sc0*8;
  const u16* bS1 = B + ((size_t)(bn*256 + pr0 + 64 ))*K + sc0*8;
  const u16* bS2 = B + ((size_t)(bn*256 + pr0 + 128))*K + sc0*8;
  const u16* bS3 = B + ((size_t)(bn*256 + pr0 + 192))*K + sc0*8;
  const int dOfs = tid * 8;

  gload16(bS0, &Bs[0][dOfs]);        gload16(bS1, &Bs[0][4096 + dOfs]);
  gload16(bS2, &Bs[0][8192 + dOfs]); gload16(bS3, &Bs[0][12288 + dOfs]);
  gload16(aS0, &As[0][dOfs]);        gload16(aS1, &As[0][4096 + dOfs]);
  gload16(aS2, &As[0][8192 + dOfs]); gload16(aS3, &As[0][12288 + dOfs]);
  asm volatile("s_waitcnt vmcnt(0)" ::: "memory");
  __builtin_amdgcn_s_barrier();

  const int nk = K >> 6;
  for (int t = 0; t < nk; ++t){
    const int cur = t & 1, nxt = cur ^ 1;
    const u16* Ac = &As[cur][0];
    const u16* Bc = &Bs[cur][0];
    u16* An = &As[nxt][0];
    u16* Bn = &Bs[nxt][0];
    const size_t ko = (size_t)(t + 1) * 64;
    const bool more = (t + 1 < nk);
    short8 avr[4], bvr[8];

    #define RD_A(q) \
      _Pragma("unroll") for (int mt = 0; mt < 2; mt++) \
        _Pragma("unroll") for (int kk = 0; kk < 2; kk++){ \
          int ra = wr*128 + (q)*32 + mt*16 + lo; \
          int fo = ((ra & 63) << 6) + ((ra & 64) ? 8192 : 0) + ((ra & 128) ? 4096 : 0) \
                 + ((((kk << 2) + hi) ^ sw) << 3); \
          avr[mt*2 + kk] = *(const short8*)&Ac[fo]; \
        }
    #define DO_MFMA(q) \
      __builtin_amdgcn_s_setprio(1); \
      _Pragma("unroll") for (int mt = 0; mt < 2; mt++) \
        _Pragma("unroll") for (int nt = 0; nt < 4; nt++) \
          _Pragma("unroll") for (int kk = 0; kk < 2; kk++) \
            acc[(q)*2 + mt][nt] = MFMA_(avr[mt*2 + kk], bvr[nt*2 + kk], acc[(q)*2 + mt][nt]); \
      __builtin_amdgcn_s_setprio(0);

    #pragma unroll
    for (int nt = 0; nt < 4; nt++)
      #pragma unroll
      for (int kk = 0; kk < 2; kk++){
        int rb = wc*64 + nt*16 + lo;
        int fo = (rb << 6) + ((((kk << 2) + hi) ^ sw) << 3);
        bvr[nt*2 + kk] = *(const short8*)&Bc[fo];
      }
    RD_A(0)
    if (more){ gload16(bS0 + ko, Bn + dOfs); gload16(bS1 + ko, Bn + 4096 + dOfs); }
    __builtin_amdgcn_s_barrier();
    DO_MFMA(0)
    __builtin_amdgcn_s_barrier();

    RD_A(1)
    if (more){
      gload16(bS2 + ko, Bn + 8192 + dOfs); gload16(bS3 + ko, Bn + 12288 + dOfs);
      asm volatile("s_waitcnt vmcnt(4)" ::: "memory");
    } else {
      asm volatile("s_waitcnt vmcnt(0)" ::: "memory");
    }
    __builtin_amdgcn_sched_barrier(0);
    __builtin_amdgcn_s_barrier();
    DO_MFMA(1)
    __builtin_amdgcn_s_barrier();

    RD_A(2)
    if (more){ gload16(aS0 + ko, An + dOfs); gload16(aS1 + ko, An + 4096 + dOfs); }
    __builtin_amdgcn_s_barrier();
    DO_MFMA(2)
    __builtin_amdgcn_s_barrier();

    RD_A(3)
    if (more){ gload16(aS2 + ko, An + 8192 + dOfs); gload16(aS3 + ko, An + 12288 + dOfs); }
    asm volatile("s_waitcnt vmcnt(2)" ::: "memory");
    __builtin_amdgcn_sched_barrier(0);
    __builtin_amdgcn_s_barrier();
    DO_MFMA(3)
    __builtin_amdgcn_s_barrier();
    #undef RD_A
    #undef DO_MFMA
  }

  #pragma unroll
  for (int mtg = 0; mtg < 8; mtg++){
    int row = bm*256 + wr*128 + mtg*16 + 4*hi;
    #pragma unroll
    for (int nt = 0; nt < 4; nt++){
      int col = bn*256 + wc*64 + nt*16 + lo;
      #pragma unroll
      for (int r = 0; r < 4; r++)
        C[(size_t)(row + r)*N + col] = acc[mtg][nt][r];
    }
  }
}

// ---------------- fused windowed-causal GQA flash attention (32x32 MFMA, QBLK=128) ----------------
// 1D grid 1024: id&7 = hkv (XCD pin), qt scrambled (+3*gb) for load balance.
// 4 waves x 32 q-rows. Swapped QK^T (A=K, B=Q). P -> PV A-frags via cvt_pk+permlane (T12).
// LDS 64 KB (K dbuf + V^T dbuf) -> 2 blocks/CU. VGPR needs ~200 -> 2 waves/SIMD is the
// floor (HW VGPR steps 64/128/256; min-3-waves bound forces spills -- measured R10).
__global__ __launch_bounds__(256, 2) void attn_kernel(const u16* __restrict__ qkv, u16* __restrict__ out,
                                                      const int* __restrict__ winp,
                                                      const int* __restrict__ pos_ids,
                                                      const float2* __restrict__ tab){
  const int id = blockIdx.x;
  const int hkv = id & 7;
  const int qtr = (id >> 3) & 15;
  const int gb  = id >> 7;
  const int qt  = (qtr + 3*gb) & 15;
  const int g = gb & 3, b = gb >> 2;
  const int h = hkv*4 + g;
  const int q0 = qt * 128;
  const int tid = threadIdx.x, wave = tid >> 6, lane = tid & 63;
  const int ql = lane & 31, hl = lane >> 5;
  const int win = winp[0];

  __shared__ u16 Ks[2][64*128];   // [j][d], 16-slot XOR swizzle (slot ^= j&15)
  __shared__ u16 VT[2][128*64];   // [d][j], 8-slot XOR swizzle (4-word groups)

  const int qw = q0 + wave*32;
  short8 qf[8];
  {
    const u16* qp = qkv + (size_t)(b*S_ + qw + ql)*QKVW_ + h*D_ + hl*8;
    #pragma unroll
    for (int c = 0; c < 8; c++) qf[c] = *(const short8*)(qp + c*16);
    const float QS = 0.08838834764831845f * 1.4426950408889634f;
    int pos = pos_ids[b*S_ + qw + ql];
    const float2* tb = tab + pos*64 + hl*8;
    #pragma unroll
    for (int c = 0; c < 4; c++)
      #pragma unroll
      for (int i = 0; i < 8; i++){
        float2 cs = tb[c*16 + i];
        float x1 = bf2f((u16)qf[c][i]), x2 = bf2f((u16)qf[c+4][i]);
        qf[c][i]   = (short)bfc((x1*cs.x - x2*cs.y) * QS);
        qf[c+4][i] = (short)bfc((x2*cs.x + x1*cs.y) * QS);
      }
  }

  f32x16 acc[4] = {};
  float m_r = -3.0e38f, l_r = 0.0f;

  int js = q0 - (win - 1); if (js < 0) js = 0; js &= ~63;
  const int nt = (q0 + 128 - js) >> 6;

  const u16* Kg = qkv + (size_t)HID_ + hkv*D_;
  const u16* Vg = qkv + (size_t)HID_ + HKV_*D_ + hkv*D_;
  const int jp = tid & 31, d0 = (tid >> 5) * 16;

  const u16* ksrc[4];
  #pragma unroll
  for (int p = 0; p < 4; p++){
    int e = p*256 + tid;
    int row = e >> 4;
    int ss = (e & 15) ^ (row & 15);
    ksrc[p] = Kg + (size_t)(b*S_ + js + row)*QKVW_ + ss*8;
  }
  const u16* vsrc = Vg + (size_t)(b*S_ + js + 2*jp)*QKVW_ + d0;

  u16x8 vr0, vr1, vr2, vr3;
  {
    #pragma unroll
    for (int p = 0; p < 4; p++) gload16(ksrc[p], &Ks[0][p*2048 + wave*512]);
    vr0 = *(const u16x8*)(vsrc);
    vr1 = *(const u16x8*)(vsrc + 8);
    vr2 = *(const u16x8*)(vsrc + QKVW_);
    vr3 = *(const u16x8*)(vsrc + QKVW_ + 8);
    uint32_t* VT32 = (uint32_t*)&VT[0][0];
    #pragma unroll
    for (int i = 0; i < 8; i++){
      int da = d0 + i, db = d0 + 8 + i;
      VT32[da*32 + (jp ^ ((da & 7) << 2))] = (uint32_t)vr0[i] | ((uint32_t)vr2[i] << 16);
      VT32[db*32 + (jp ^ ((db & 7) << 2))] = (uint32_t)vr1[i] | ((uint32_t)vr3[i] << 16);
    }
  }
  __syncthreads();

  for (int t = 0; t < nt; t++){
    const int jc = js + t*64;
    const int cur = t & 1, nxt = cur ^ 1;
    const bool more = (t + 1 < nt);
    if (more){
      const size_t adv = (size_t)(t+1) * 64 * QKVW_;
      #pragma unroll
      for (int p = 0; p < 4; p++) gload16(ksrc[p] + adv, &Ks[nxt][p*2048 + wave*512]);
      const u16* vp = vsrc + adv;
      vr0 = *(const u16x8*)(vp);
      vr1 = *(const u16x8*)(vp + 8);
      vr2 = *(const u16x8*)(vp + QKVW_);
      vr3 = *(const u16x8*)(vp + QKVW_ + 8);
    }
    if (jc <= qw + 31 && jc + 63 >= qw - win + 1){
      // ---- QK^T: A=K rows j, B=Q cols q ----
      f32x16 s0 = {}, s1 = {};
      const int sl = ql & 15;
      __builtin_amdgcn_s_setprio(1);
      #pragma unroll
      for (int c = 0; c < 8; c++){
        int so = (((c*2 + hl) ^ sl) * 8);
        short8 k0 = *(const short8*)&Ks[cur][ql*128 + so];
        short8 k1 = *(const short8*)&Ks[cur][(32 + ql)*128 + so];
        s0 = MFMA32_(k0, qf[c], s0);
        s1 = MFMA32_(k1, qf[c], s1);
      }
      __builtin_amdgcn_s_setprio(0);
      // ---- mask ----
      const int qa = qw + ql;
      const bool fullv = (jc + 63 <= qw) && (jc >= qw + 32 - win);
      if (!fullv){
        #pragma unroll
        for (int r = 0; r < 16; r++){
          int j0 = jc + (r&3) + 8*(r>>2) + 4*hl;
          if (j0 > qa || qa - j0 >= win) s0[r] = -3.0e38f;
          int j1 = j0 + 32;
          if (j1 > qa || qa - j1 >= win) s1[r] = -3.0e38f;
        }
      }
      // ---- row max (31 in-lane + 1 xor) ----
      float mx = s0[0];
      #pragma unroll
      for (int r = 1; r < 16; r++) mx = fmaxf(mx, s0[r]);
      #pragma unroll
      for (int r = 0; r < 16; r++) mx = fmaxf(mx, s1[r]);
      mx = fmaxf(mx, __shfl_xor(mx, 32));
      // ---- defer-max rescale (T13) ----
      if (__any(mx > m_r + 8.0f)){
        float mn = fmaxf(m_r, mx);
        float al = exp2f(m_r - mn);
        m_r = mn; l_r *= al;
        #pragma unroll
        for (int r = 0; r < 16; r++){
          float a = __shfl(al, (r&3) + 8*(r>>2) + 4*hl);
          acc[0][r] *= a; acc[1][r] *= a; acc[2][r] *= a; acc[3][r] *= a;
        }
      }
      // ---- exp2 (in place) + sum ----
      float ps = 0.f;
      if (fullv){
        #pragma unroll
        for (int r = 0; r < 16; r++){
          s0[r] = exp2f(s0[r] - m_r); s1[r] = exp2f(s1[r] - m_r);
          ps += s0[r] + s1[r];
        }
      } else {
        #pragma unroll
        for (int r = 0; r < 16; r++){
          s0[r] = s0[r] > -1e37f ? exp2f(s0[r] - m_r) : 0.f;
          s1[r] = s1[r] > -1e37f ? exp2f(s1[r] - m_r) : 0.f;
          ps += s0[r] + s1[r];
        }
      }
      ps += __shfl_xor(ps, 32);
      l_r += ps;
      // ---- P -> A-frags: cvt_pk + permlane32_swap (T12) ----
      short8 pa[4];
      #define MKFRAG(dst, P, o) { \
        uint32_t x1 = cvtpk(P[o+0], P[o+1]), x2 = cvtpk(P[o+2], P[o+3]); \
        uint32_t y1 = cvtpk(P[o+4], P[o+5]), y2 = cvtpk(P[o+6], P[o+7]); \
        pl32swap(x1, y1); pl32swap(x2, y2); \
        union { uint32_t w[4]; short8 v; } u_; \
        u_.w[0] = x1; u_.w[1] = x2; u_.w[2] = y1; u_.w[3] = y2; \
        dst = u_.v; }
      MKFRAG(pa[0], s0, 0)
      MKFRAG(pa[1], s0, 8)
      MKFRAG(pa[2], s1, 0)
      MKFRAG(pa[3], s1, 8)
      #undef MKFRAG
      // ---- PV: A=P (reg), B=V^T from LDS ----
      __builtin_amdgcn_s_setprio(1);
      #pragma unroll
      for (int dt = 0; dt < 4; dt++){
        const int dr = dt*32 + ql;
        const u16* vb = &VT[cur][dr*64];
        const int sb = dr & 7;
        #pragma unroll
        for (int ks = 0; ks < 4; ks++){
          short8 vf = *(const short8*)&vb[(((ks*2 + hl) ^ sb) * 8)];
          acc[dt] = MFMA32_(pa[ks], vf, acc[dt]);
        }
      }
      __builtin_amdgcn_s_setprio(0);
    }
    if (more){
      uint32_t* VT32 = (uint32_t*)&VT[nxt][0];
      #pragma unroll
      for (int i = 0; i < 8; i++){
        int da = d0 + i, db = d0 + 8 + i;
        VT32[da*32 + (jp ^ ((da & 7) << 2))] = (uint32_t)vr0[i] | ((uint32_t)vr2[i] << 16);
        VT32[db*32 + (jp ^ ((db & 7) << 2))] = (uint32_t)vr1[i] | ((uint32_t)vr3[i] << 16);
      }
      __syncthreads();
    }
  }
  // ---- epilogue ----
  #pragma unroll
  for (int r = 0; r < 16; r++){
    int qrow = (r&3) + 8*(r>>2) + 4*hl;
    float lr = __shfl(l_r, qrow);
    float invl = 1.0f / lr;
    size_t ro = (size_t)(b*S_ + qw + qrow)*HID_ + h*D_ + ql;
    out[ro     ] = f2bf(acc[0][r] * invl);
    out[ro + 32] = f2bf(acc[1][r] * invl);
    out[ro + 64] = f2bf(acc[2][r] * invl);
    out[ro + 96] = f2bf(acc[3][r] * invl);
  }
}

extern "C" void kernel_launch(void* const* d_in, const int* in_sizes, int n_in,
                              void* d_out, int out_size, void* d_ws, size_t ws_size,
                              hipStream_t stream) {
  const float* hs   = (const float*)d_in[0];
  const float* wqkv = (const float*)d_in[1];
  const float* wo   = (const float*)d_in[2];
  const int* pos  = (const int*)d_in[5];
  const int* winp = (const int*)d_in[7];
  float* out = (float*)d_out;

  u16* hsb = (u16*)d_ws;
  u16* wqb = hsb + (size_t)HID_*HID_;
  u16* wob = wqb + (size_t)QKVW_*HID_;
  u16* qkv = wob + (size_t)HID_*HID_;
  u16* att = qkv + (size_t)(B_*S_)*QKVW_;
  float2* tab = (float2*)(att + (size_t)(B_*S_)*HID_);

  cvt3_kernel<<<2048, 256, 0, stream>>>(hs, wqkv, wo, hsb, wqb, wob, tab);
  gemm128<<<dim3(QKVW_/128, (B_*S_)/128), 256, 0, stream>>>(hsb, wqb, qkv, B_*S_, QKVW_, HID_);
  rope_k_kernel<<<B_*S_, 256, 0, stream>>>(qkv, pos, tab);
  attn_kernel<<<1024, 256, 0, stream>>>(qkv, att, winp, pos, tab);
  gemm256<<<(B_*S_/256)*(HID_/256), 512, 0, stream>>>(att, wob, out, B_*S_, HID_, HID_, HID_/256);
}